// Round 8
// baseline (251.193 us; speedup 1.0000x reference)
//
#include <hip/hip_runtime.h>
#include <math.h>

// MultiHeadAttention: B=2, T=2048, C=1024, H=16, D=64, causal, fp32 in/out.
// R8: attn = (qhalf x keyhalf) all-active wave split + 128-key supersteps
// (half the barriers, deeper prefetch). gemm_out gets one-barrier LDS dbuf.
// Fixed-max softmax (p = exp2(s2 - 14.5), Q prescaled by 0.125*log2(e)).

#define BLOCK 256

typedef __attribute__((ext_vector_type(8))) short bf16x8;
typedef __attribute__((ext_vector_type(4))) float f32x4;
typedef __attribute__((ext_vector_type(16))) float f32x16;

__device__ inline short f2bf(float f) {
  union { float f; unsigned u; } c; c.f = f;
  unsigned u = c.u;
  unsigned r = (u + 0x7fffu + ((u >> 16) & 1u)) >> 16;  // RNE
  return (short)r;
}

// async global->LDS, 16B per lane; LDS dest must be wave-uniform base + lane*16
#define GLD_LDS16(g, l)                                            \
  __builtin_amdgcn_global_load_lds(                                \
      (const __attribute__((address_space(1))) unsigned int*)(g),  \
      (__attribute__((address_space(3))) unsigned int*)(l), 16, 0, 0)

// ---------------- conversion kernels ----------------

__global__ void cvt_x_kernel(const float* __restrict__ x, short* __restrict__ xb) {
  int i = (blockIdx.x * BLOCK + threadIdx.x) * 8;
  float4 a = *(const float4*)(x + i);
  float4 b = *(const float4*)(x + i + 4);
  alignas(16) short o[8];
  o[0] = f2bf(a.x); o[1] = f2bf(a.y); o[2] = f2bf(a.z); o[3] = f2bf(a.w);
  o[4] = f2bf(b.x); o[5] = f2bf(b.y); o[6] = f2bf(b.z); o[7] = f2bf(b.w);
  *(int4*)(xb + i) = *(int4*)o;
}

// W [1024 (in,k)][1024 (out,n)] fp32 -> Wt [n][k] bf16 (tiled transpose)
__global__ void cvt_w_kernel(const float* __restrict__ Wq, const float* __restrict__ Wk,
                             const float* __restrict__ Wv, const float* __restrict__ Wo,
                             short* __restrict__ Wtqkv, short* __restrict__ Wto) {
  __shared__ float tile[32][33];
  int z = blockIdx.z;
  const float* W = (z == 0) ? Wq : (z == 1) ? Wk : (z == 2) ? Wv : Wo;
  short* outp = (z == 3) ? Wto : (Wtqkv + (size_t)z * 1024 * 1024);
  int k0 = blockIdx.x * 32, n0 = blockIdx.y * 32;
  int tr = threadIdx.x >> 5, tc = threadIdx.x & 31;
#pragma unroll
  for (int i = 0; i < 4; i++)
    tile[tr + i * 8][tc] = W[(k0 + tr + i * 8) * 1024 + n0 + tc];
  __syncthreads();
#pragma unroll
  for (int i = 0; i < 4; i++)
    outp[(n0 + tr + i * 8) * 1024 + k0 + tc] = f2bf(tile[tc][tr + i * 8]);
}

// ---------------- fused QKV GEMM ----------------
// A [4096][1024] bf16 (x), Wt [3072][1024] bf16 (B^T). BK=32, one-barrier
// LDS double-buffer: barrier -> issue loads(next) -> compute(cur).
// Q -> [B,H,T,D] prescaled by 0.125*log2(e); K -> [B,H,T,D];
// V -> V^T [B,H,D,T] (natural key order), b64-packed stores.

__global__ __launch_bounds__(BLOCK) void gemm_qkv_kernel(
    const short* __restrict__ A, const short* __restrict__ Wt,
    const float* __restrict__ bq, const float* __restrict__ bk,
    const float* __restrict__ bv,
    short* __restrict__ Qo, short* __restrict__ Ko, short* __restrict__ Vo) {
  const int Kd = 1024;
  const float QSCL = 0.18033688011f;  // 0.125 * log2(e)
  int m0 = blockIdx.x * 128, n0 = blockIdx.y * 128;
  int t = threadIdx.x;
  int lane = t & 63, wv = t >> 6;
  int quad = lane >> 4, lc = lane & 15;
  int wy = wv >> 1, wx = wv & 1;
  __shared__ short As[2][128 * 32];
  __shared__ short Bs[2][128 * 32];
  f32x4 acc[4][4] = {};
  int r0 = t >> 2, c0 = (t & 3) * 8;  // As[p][r0*32+c0] == As[p][8*t]
  const short* Arow0 = A + (size_t)(m0 + r0) * Kd + c0;
  const short* Arow1 = A + (size_t)(m0 + r0 + 64) * Kd + c0;
  const short* Brow0 = Wt + (size_t)(n0 + r0) * Kd + c0;
  const short* Brow1 = Wt + (size_t)(n0 + r0 + 64) * Kd + c0;
  // prologue: stage k=0 into buf 0
  GLD_LDS16(Arow0, &As[0][8 * t]);
  GLD_LDS16(Arow1, &As[0][8 * t + 2048]);
  GLD_LDS16(Brow0, &Bs[0][8 * t]);
  GLD_LDS16(Brow1, &Bs[0][8 * t + 2048]);
  int cur = 0;
  for (int k0 = 0; k0 < Kd; k0 += 32) {
    __syncthreads();  // drains cur's loads (issued one full compute ago)
    if (k0 + 32 < Kd) {
      int nxt = cur ^ 1;
      GLD_LDS16(Arow0 + k0 + 32, &As[nxt][8 * t]);
      GLD_LDS16(Arow1 + k0 + 32, &As[nxt][8 * t + 2048]);
      GLD_LDS16(Brow0 + k0 + 32, &Bs[nxt][8 * t]);
      GLD_LDS16(Brow1 + k0 + 32, &Bs[nxt][8 * t + 2048]);
    }
    bf16x8 af[4], bf[4];
#pragma unroll
    for (int i = 0; i < 4; i++)
      af[i] = *(const bf16x8*)&As[cur][(wy * 64 + i * 16 + lc) * 32 + quad * 8];
#pragma unroll
    for (int i = 0; i < 4; i++)
      bf[i] = *(const bf16x8*)&Bs[cur][(wx * 64 + i * 16 + lc) * 32 + quad * 8];
#pragma unroll
    for (int mi = 0; mi < 4; mi++)
#pragma unroll
      for (int ni = 0; ni < 4; ni++)
        acc[mi][ni] = __builtin_amdgcn_mfma_f32_16x16x32_bf16(af[mi], bf[ni], acc[mi][ni], 0, 0, 0);
    cur ^= 1;
  }
#pragma unroll
  for (int mi = 0; mi < 4; mi++) {
    int row = m0 + wy * 64 + mi * 16 + quad * 4;
#pragma unroll
    for (int ni = 0; ni < 4; ni++) {
      int col = n0 + wx * 64 + ni * 16 + lc;
      int which = col >> 10;  // block-uniform (n-tile never straddles 1024)
      int hd = col & 1023;
      int h = hd >> 6, d = hd & 63;
      float bb = (which == 0) ? bq[hd] : (which == 1) ? bk[hd] : bv[hd];
      if (which == 2) {  // V^T [b,h,d,t], pack 4 consecutive t
        alignas(8) short pk[4];
#pragma unroll
        for (int r = 0; r < 4; r++) pk[r] = f2bf(acc[mi][ni][r] + bb);
        int b = row >> 11, tt = row & 2047;
        *(int2*)&Vo[((size_t)(b * 16 + h) * 64 + d) * 2048 + tt] = *(const int2*)pk;
      } else {
#pragma unroll
        for (int r = 0; r < 4; r++) {
          int rw = row + r;
          int b = rw >> 11, tt = rw & 2047;
          float val = acc[mi][ni][r] + bb;
          if (which == 0) {
            Qo[((size_t)(b * 16 + h) * 2048 + tt) * 64 + d] = f2bf(val * QSCL);
          } else {
            Ko[((size_t)(b * 16 + h) * 2048 + tt) * 64 + d] = f2bf(val);
          }
        }
      }
    }
  }
}

// ---------------- out-projection GEMM ----------------
// A = attended [4096][1024] bf16, Wt = Wo^T [1024][1024], out fp32.
// 64x128 tile, grid (64,8) = 512 blocks; one-barrier LDS dbuf.

__global__ __launch_bounds__(BLOCK) void gemm_out_kernel(
    const short* __restrict__ A, const short* __restrict__ Wt,
    const float* __restrict__ bias, float* __restrict__ Out) {
  const int Kd = 1024;
  int m0 = blockIdx.x * 64, n0 = blockIdx.y * 128;
  int t = threadIdx.x;
  int lane = t & 63, wv = t >> 6;
  int quad = lane >> 4, lc = lane & 15;
  int wy = wv >> 1, wx = wv & 1;  // wave tile: rows wy*32, cols wx*64
  __shared__ short As[2][64 * 32];
  __shared__ short Bs[2][128 * 32];
  int r0 = t >> 2, c0 = (t & 3) * 8;
  f32x4 acc[2][4] = {};
  const short* Arow0 = A + (size_t)(m0 + r0) * Kd + c0;  // r0 covers 0..63
  const short* Brow0 = Wt + (size_t)(n0 + r0) * Kd + c0;
  const short* Brow1 = Wt + (size_t)(n0 + r0 + 64) * Kd + c0;
  GLD_LDS16(Arow0, &As[0][8 * t]);
  GLD_LDS16(Brow0, &Bs[0][8 * t]);
  GLD_LDS16(Brow1, &Bs[0][8 * t + 2048]);
  int cur = 0;
  for (int k0 = 0; k0 < Kd; k0 += 32) {
    __syncthreads();
    if (k0 + 32 < Kd) {
      int nxt = cur ^ 1;
      GLD_LDS16(Arow0 + k0 + 32, &As[nxt][8 * t]);
      GLD_LDS16(Brow0 + k0 + 32, &Bs[nxt][8 * t]);
      GLD_LDS16(Brow1 + k0 + 32, &Bs[nxt][8 * t + 2048]);
    }
    bf16x8 af[2], bf[4];
#pragma unroll
    for (int i = 0; i < 2; i++)
      af[i] = *(const bf16x8*)&As[cur][(wy * 32 + i * 16 + lc) * 32 + quad * 8];
#pragma unroll
    for (int i = 0; i < 4; i++)
      bf[i] = *(const bf16x8*)&Bs[cur][(wx * 64 + i * 16 + lc) * 32 + quad * 8];
#pragma unroll
    for (int mi = 0; mi < 2; mi++)
#pragma unroll
      for (int ni = 0; ni < 4; ni++)
        acc[mi][ni] = __builtin_amdgcn_mfma_f32_16x16x32_bf16(af[mi], bf[ni], acc[mi][ni], 0, 0, 0);
    cur ^= 1;
  }
#pragma unroll
  for (int mi = 0; mi < 2; mi++) {
    int row = m0 + wy * 32 + mi * 16 + quad * 4;
#pragma unroll
    for (int ni = 0; ni < 4; ni++) {
      int col = n0 + wx * 64 + ni * 16 + lc;
      float bb = bias[col];
#pragma unroll
      for (int r = 0; r < 4; r++)
        Out[(size_t)(row + r) * 1024 + col] = acc[mi][ni][r] + bb;
    }
  }
}

// ---------------- flash attention v8 ----------------
// Grid 512 = 32 bh x 16 strip-pairs; strip = 64 q; pair (s, 31-s) -> uniform
// 33 key-tiles/block. 4 waves = qhalf(w&1) x keyhalf(w>>1): every wave active
// every tile (32-key group of each 64-key tile for its 32 q rows). 128-key
// supersteps: stage 2 tiles per barrier round. Fixed-max softmax; kh partials
// exactly additive; combine via LDS (dead P region) at strip end.
// 32x32x16 MFMA. C-layout: col=lane&31, row=(reg&3)+8*(reg>>2)+4*(lane>>5).

__global__ __launch_bounds__(BLOCK, 2) void attn_kernel(
    const short* __restrict__ Q, const short* __restrict__ K,
    const short* __restrict__ Vt, short* __restrict__ Oa) {
  int bh = blockIdx.x >> 4;    // 0..31
  int pair = blockIdx.x & 15;  // 0..15
  int t = threadIdx.x;
  int lane = t & 63, w = t >> 6;
  int qh = w & 1, kh = w >> 1;
  int ln = lane & 31, lh = lane >> 5;
  const short* Qb = Q + (size_t)bh * 2048 * 64;
  const short* Kb = K + (size_t)bh * 2048 * 64;
  const short* Vg = Vt + (size_t)bh * 64 * 2048;
  int b = bh >> 4, h = bh & 15;

  __shared__ short Kt[128 * 72];    // [key 128][d 64], stride 72
  __shared__ short Vs[64 * 136];    // [d 64][key 128], stride 136
  __shared__ __align__(16) short Ps[4][32 * 72];  // per-wave P [q 32][slot 64]; reused as O-combine
  __shared__ float lx[2][64];
  short* Pw = Ps[w];

  // staging coords: K by half-rows, V^T by quarter-rows
  int krow = t >> 1, khalf = (t & 1) * 32;  // K row 0..127, 32-short half
  int vrow = t >> 2, vq = (t & 3) * 32;     // V d-row 0..63, 32-key group
  const float M2 = 14.5f;                   // fixed softmax max, log2 domain

  for (int sp = 0; sp < 2; sp++) {
    int s = sp ? (31 - pair) : pair;
    int q0 = s * 64;
    int q0w = q0 + qh * 32;
    int qmax = q0w + 31;
    int ntiles = s + 1;
    int nss = (ntiles + 1) >> 1;

    // Q B-frags (n=q, k=d), 4 chunks of 16 d
    bf16x8 qf[4];
#pragma unroll
    for (int c = 0; c < 4; c++)
      qf[c] = *(const bf16x8*)&Qb[(size_t)(q0w + ln) * 64 + c * 16 + lh * 8];

    f32x16 O0 = {}, O1 = {};
    float lsum = 0.f;

    // prologue: stage superstep 0
    int4 kreg[4], vreg[4];
#pragma unroll
    for (int i = 0; i < 4; i++) {
      kreg[i] = *(const int4*)&Kb[(size_t)krow * 64 + khalf + i * 8];
      vreg[i] = *(const int4*)&Vg[(size_t)vrow * 2048 + vq + i * 8];
    }
    __syncthreads();  // previous strip's readers done
#pragma unroll
    for (int i = 0; i < 4; i++) {
      *(int4*)&Kt[krow * 72 + khalf + i * 8] = kreg[i];
      *(int4*)&Vs[vrow * 136 + vq + i * 8] = vreg[i];
    }
    __syncthreads();

    for (int ss = 0; ss < nss; ss++) {
      if (ss + 1 < nss) {  // prefetch next superstep into regs
        int kb2 = (ss + 1) * 128;
#pragma unroll
        for (int i = 0; i < 4; i++) {
          kreg[i] = *(const int4*)&Kb[(size_t)(kb2 + krow) * 64 + khalf + i * 8];
          vreg[i] = *(const int4*)&Vg[(size_t)vrow * 2048 + kb2 + vq + i * 8];
        }
      }
      bool gv[2];
#pragma unroll
      for (int st = 0; st < 2; st++) {
        int kt = ss * 2 + st;
        int grpbase = kt * 64 + kh * 32;  // wave-uniform
        gv[st] = (kt < ntiles) && (grpbase <= qmax);
        if (!gv[st]) continue;
        // S^T = K(group) * Q^T : C[m=key32][n=q32]
        f32x16 S = {};
#pragma unroll
        for (int c = 0; c < 4; c++) {
          bf16x8 kf = *(const bf16x8*)&Kt[(st * 64 + kh * 32 + ln) * 72 + c * 16 + lh * 8];
          S = __builtin_amdgcn_mfma_f32_32x32x16_bf16(kf, qf[c], S, 0, 0, 0);
        }
        if (kt == ntiles - 1) {  // diagonal tile: mask key > q
          int qg = q0w + ln;
#pragma unroll
          for (int reg = 0; reg < 16; reg++) {
            int key = grpbase + (reg & 3) + 8 * (reg >> 2) + 4 * lh;
            if (key > qg) S[reg] = -3.0e38f;
          }
        }
        // p = exp2(s - M2); accumulate l; pack 4 keys -> b64 at slot st*32+..
#pragma unroll
        for (int g = 0; g < 4; g++) {
          unsigned u[4];
#pragma unroll
          for (int i = 0; i < 4; i++) {
            union { float f; unsigned v; } cc;
            cc.f = __builtin_amdgcn_exp2f(S[g * 4 + i] - M2);
            lsum += cc.f;
            u[i] = cc.v + 0x8000u;  // round-half-up before truncate
          }
          int2 pk;
          pk.x = (int)__builtin_amdgcn_perm(u[1], u[0], 0x07060302);
          pk.y = (int)__builtin_amdgcn_perm(u[3], u[2], 0x07060302);
          *(int2*)&Pw[ln * 72 + st * 32 + g * 8 + lh * 4] = pk;
        }
      }
      // PV: O^T += V^T * P over this wave's valid key slots (per-wave LDS,
      // in-order DS, no barrier). Chunk c covers slots c*16+lh*8..+7.
#pragma unroll
      for (int c = 0; c < 4; c++) {
        if (!gv[c >> 1]) continue;
        bf16x8 pf = *(const bf16x8*)&Pw[ln * 72 + c * 16 + lh * 8];
        int vb = (c >> 1) * 64 + kh * 32 + (c & 1) * 16 + lh * 8;  // abs key
        bf16x8 v0 = *(const bf16x8*)&Vs[ln * 136 + vb];
        bf16x8 v1 = *(const bf16x8*)&Vs[(32 + ln) * 136 + vb];
        O0 = __builtin_amdgcn_mfma_f32_32x32x16_bf16(v0, pf, O0, 0, 0, 0);
        O1 = __builtin_amdgcn_mfma_f32_32x32x16_bf16(v1, pf, O1, 0, 0, 0);
      }
      if (ss + 1 < nss) {  // commit prefetched superstep
        __syncthreads();
#pragma unroll
        for (int i = 0; i < 4; i++) {
          *(int4*)&Kt[krow * 72 + khalf + i * 8] = kreg[i];
          *(int4*)&Vs[vrow * 136 + vq + i * 8] = vreg[i];
        }
        __syncthreads();
      }
    }

    // ---- combine keyhalf partials through LDS (P region is dead) ----
    float* ob = (float*)&Ps[0][0];  // [qh][((dh*16+reg)*2+lh)*32+ln] fp32
    __syncthreads();                // all P reads done before overwrite
    if (kh == 1) {
      float* obw = ob + qh * 2048;
#pragma unroll
      for (int dh = 0; dh < 2; dh++)
#pragma unroll
        for (int reg = 0; reg < 16; reg++)
          obw[((dh * 16 + reg) * 2 + lh) * 32 + ln] = dh ? O1[reg] : O0[reg];
      lx[qh][lane] = lsum;
    }
    __syncthreads();
    if (kh == 0) {
      float* obw = ob + qh * 2048;
#pragma unroll
      for (int reg = 0; reg < 16; reg++) {
        O0[reg] += obw[((0 * 16 + reg) * 2 + lh) * 32 + ln];
        O1[reg] += obw[((1 * 16 + reg) * 2 + lh) * 32 + ln];
      }
      float lt = lsum + lx[qh][lane];
      lt += __shfl_xor(lt, 32, 64);
      float inv = 1.0f / lt;
      size_t rowbase = (size_t)(b * 2048 + q0w + ln) * 1024 + h * 64;
#pragma unroll
      for (int dh = 0; dh < 2; dh++)
#pragma unroll
        for (int g = 0; g < 4; g++) {
          alignas(8) short pk[4];
#pragma unroll
          for (int i = 0; i < 4; i++) {
            float v = dh ? O1[g * 4 + i] : O0[g * 4 + i];
            pk[i] = f2bf(v * inv);
          }
          *(int2*)&Oa[rowbase + dh * 32 + g * 8 + lh * 4] = *(const int2*)pk;
        }
    }
  }
}

// ---------------- launcher ----------------

extern "C" void kernel_launch(void* const* d_in, const int* in_sizes, int n_in,
                              void* d_out, int out_size, void* d_ws, size_t ws_size,
                              hipStream_t stream) {
  const float* x = (const float*)d_in[0];
  const float* Wq = (const float*)d_in[1];
  const float* bq = (const float*)d_in[2];
  const float* Wk = (const float*)d_in[3];
  const float* bk = (const float*)d_in[4];
  const float* Wv = (const float*)d_in[5];
  const float* bv = (const float*)d_in[6];
  const float* Wo = (const float*)d_in[7];
  const float* bo = (const float*)d_in[8];
  char* ws = (char*)d_ws;
  const size_t MB = 1024 * 1024;
  short* xb = (short*)(ws);               // 8 MiB  [4096][1024] bf16
  short* Wtqkv = (short*)(ws + 8 * MB);   // 6 MiB  [3072][1024] bf16
  short* Wto = (short*)(ws + 14 * MB);    // 2 MiB  [1024][1024] bf16
  short* Qb = (short*)(ws + 17 * MB);     // 8 MiB  [2][16][2048][64] bf16 (prescaled)
  short* Kb = (short*)(ws + 25 * MB);     // 8 MiB  [2][16][2048][64] bf16
  short* Vb = (short*)(ws + 33 * MB);     // 8 MiB  V^T [2][16][64][2048] bf16
  short* Att = (short*)(ws + 41 * MB);    // 8 MiB  [4096][1024] bf16
  float* out = (float*)d_out;

  cvt_x_kernel<<<2048, BLOCK, 0, stream>>>(x, xb);
  cvt_w_kernel<<<dim3(32, 32, 4), BLOCK, 0, stream>>>(Wq, Wk, Wv, Wo, Wtqkv, Wto);
  gemm_qkv_kernel<<<dim3(32, 24), BLOCK, 0, stream>>>(xb, Wtqkv, bq, bk, bv, Qb, Kb, Vb);
  attn_kernel<<<512, BLOCK, 0, stream>>>(Qb, Kb, Vb, Att);
  gemm_out_kernel<<<dim3(64, 8), BLOCK, 0, stream>>>(Att, Wto, bo, out);
}

// Round 9
// 216.687 us; speedup vs baseline: 1.1592x; 1.1592x over previous
//
#include <hip/hip_runtime.h>
#include <math.h>

// MultiHeadAttention: B=2, T=2048, C=1024, H=16, D=64, causal, fp32 in/out.
// R9: attn = 128-thread blocks, grid 1024 (32q strip-pairs), 2 waves split
// each 64-key tile by key-half (all-active), v7-verified staging (stride 72,
// NAMED prefetch scalars - v8's arrays went to scratch: +95MB HBM writes).
// Fixed-max softmax (p = exp2(s2 - 14.5), Q prescaled by 0.125*log2(e)).

#define BLOCK 256

typedef __attribute__((ext_vector_type(8))) short bf16x8;
typedef __attribute__((ext_vector_type(4))) float f32x4;
typedef __attribute__((ext_vector_type(16))) float f32x16;

__device__ inline short f2bf(float f) {
  union { float f; unsigned u; } c; c.f = f;
  unsigned u = c.u;
  unsigned r = (u + 0x7fffu + ((u >> 16) & 1u)) >> 16;  // RNE
  return (short)r;
}

// async global->LDS, 16B per lane; LDS dest must be wave-uniform base + lane*16
#define GLD_LDS16(g, l)                                            \
  __builtin_amdgcn_global_load_lds(                                \
      (const __attribute__((address_space(1))) unsigned int*)(g),  \
      (__attribute__((address_space(3))) unsigned int*)(l), 16, 0, 0)

// ---------------- conversion kernels ----------------

__global__ void cvt_x_kernel(const float* __restrict__ x, short* __restrict__ xb) {
  int i = (blockIdx.x * BLOCK + threadIdx.x) * 8;
  float4 a = *(const float4*)(x + i);
  float4 b = *(const float4*)(x + i + 4);
  alignas(16) short o[8];
  o[0] = f2bf(a.x); o[1] = f2bf(a.y); o[2] = f2bf(a.z); o[3] = f2bf(a.w);
  o[4] = f2bf(b.x); o[5] = f2bf(b.y); o[6] = f2bf(b.z); o[7] = f2bf(b.w);
  *(int4*)(xb + i) = *(int4*)o;
}

// W [1024 (in,k)][1024 (out,n)] fp32 -> Wt [n][k] bf16 (tiled transpose)
__global__ void cvt_w_kernel(const float* __restrict__ Wq, const float* __restrict__ Wk,
                             const float* __restrict__ Wv, const float* __restrict__ Wo,
                             short* __restrict__ Wtqkv, short* __restrict__ Wto) {
  __shared__ float tile[32][33];
  int z = blockIdx.z;
  const float* W = (z == 0) ? Wq : (z == 1) ? Wk : (z == 2) ? Wv : Wo;
  short* outp = (z == 3) ? Wto : (Wtqkv + (size_t)z * 1024 * 1024);
  int k0 = blockIdx.x * 32, n0 = blockIdx.y * 32;
  int tr = threadIdx.x >> 5, tc = threadIdx.x & 31;
#pragma unroll
  for (int i = 0; i < 4; i++)
    tile[tr + i * 8][tc] = W[(k0 + tr + i * 8) * 1024 + n0 + tc];
  __syncthreads();
#pragma unroll
  for (int i = 0; i < 4; i++)
    outp[(n0 + tr + i * 8) * 1024 + k0 + tc] = f2bf(tile[tc][tr + i * 8]);
}

// ---------------- fused QKV GEMM ----------------
// A [4096][1024] bf16 (x), Wt [3072][1024] bf16 (B^T). BK=32, one-barrier
// LDS double-buffer: barrier -> issue loads(next) -> compute(cur).
// Q -> [B,H,T,D] prescaled by 0.125*log2(e); K -> [B,H,T,D];
// V -> V^T [B,H,D,T] (natural key order), b64-packed stores.

__global__ __launch_bounds__(BLOCK) void gemm_qkv_kernel(
    const short* __restrict__ A, const short* __restrict__ Wt,
    const float* __restrict__ bq, const float* __restrict__ bk,
    const float* __restrict__ bv,
    short* __restrict__ Qo, short* __restrict__ Ko, short* __restrict__ Vo) {
  const int Kd = 1024;
  const float QSCL = 0.18033688011f;  // 0.125 * log2(e)
  int m0 = blockIdx.x * 128, n0 = blockIdx.y * 128;
  int t = threadIdx.x;
  int lane = t & 63, wv = t >> 6;
  int quad = lane >> 4, lc = lane & 15;
  int wy = wv >> 1, wx = wv & 1;
  __shared__ short As[2][128 * 32];
  __shared__ short Bs[2][128 * 32];
  f32x4 acc[4][4] = {};
  int r0 = t >> 2, c0 = (t & 3) * 8;  // As[p][r0*32+c0] == As[p][8*t]
  const short* Arow0 = A + (size_t)(m0 + r0) * Kd + c0;
  const short* Arow1 = A + (size_t)(m0 + r0 + 64) * Kd + c0;
  const short* Brow0 = Wt + (size_t)(n0 + r0) * Kd + c0;
  const short* Brow1 = Wt + (size_t)(n0 + r0 + 64) * Kd + c0;
  // prologue: stage k=0 into buf 0
  GLD_LDS16(Arow0, &As[0][8 * t]);
  GLD_LDS16(Arow1, &As[0][8 * t + 2048]);
  GLD_LDS16(Brow0, &Bs[0][8 * t]);
  GLD_LDS16(Brow1, &Bs[0][8 * t + 2048]);
  int cur = 0;
  for (int k0 = 0; k0 < Kd; k0 += 32) {
    __syncthreads();  // drains cur's loads (issued one full compute ago)
    if (k0 + 32 < Kd) {
      int nxt = cur ^ 1;
      GLD_LDS16(Arow0 + k0 + 32, &As[nxt][8 * t]);
      GLD_LDS16(Arow1 + k0 + 32, &As[nxt][8 * t + 2048]);
      GLD_LDS16(Brow0 + k0 + 32, &Bs[nxt][8 * t]);
      GLD_LDS16(Brow1 + k0 + 32, &Bs[nxt][8 * t + 2048]);
    }
    bf16x8 af[4], bf[4];
#pragma unroll
    for (int i = 0; i < 4; i++)
      af[i] = *(const bf16x8*)&As[cur][(wy * 64 + i * 16 + lc) * 32 + quad * 8];
#pragma unroll
    for (int i = 0; i < 4; i++)
      bf[i] = *(const bf16x8*)&Bs[cur][(wx * 64 + i * 16 + lc) * 32 + quad * 8];
#pragma unroll
    for (int mi = 0; mi < 4; mi++)
#pragma unroll
      for (int ni = 0; ni < 4; ni++)
        acc[mi][ni] = __builtin_amdgcn_mfma_f32_16x16x32_bf16(af[mi], bf[ni], acc[mi][ni], 0, 0, 0);
    cur ^= 1;
  }
#pragma unroll
  for (int mi = 0; mi < 4; mi++) {
    int row = m0 + wy * 64 + mi * 16 + quad * 4;
#pragma unroll
    for (int ni = 0; ni < 4; ni++) {
      int col = n0 + wx * 64 + ni * 16 + lc;
      int which = col >> 10;  // block-uniform (n-tile never straddles 1024)
      int hd = col & 1023;
      int h = hd >> 6, d = hd & 63;
      float bb = (which == 0) ? bq[hd] : (which == 1) ? bk[hd] : bv[hd];
      if (which == 2) {  // V^T [b,h,d,t], pack 4 consecutive t
        alignas(8) short pk[4];
#pragma unroll
        for (int r = 0; r < 4; r++) pk[r] = f2bf(acc[mi][ni][r] + bb);
        int b = row >> 11, tt = row & 2047;
        *(int2*)&Vo[((size_t)(b * 16 + h) * 64 + d) * 2048 + tt] = *(const int2*)pk;
      } else {
#pragma unroll
        for (int r = 0; r < 4; r++) {
          int rw = row + r;
          int b = rw >> 11, tt = rw & 2047;
          float val = acc[mi][ni][r] + bb;
          if (which == 0) {
            Qo[((size_t)(b * 16 + h) * 2048 + tt) * 64 + d] = f2bf(val * QSCL);
          } else {
            Ko[((size_t)(b * 16 + h) * 2048 + tt) * 64 + d] = f2bf(val);
          }
        }
      }
    }
  }
}

// ---------------- out-projection GEMM ----------------
// A = attended [4096][1024] bf16, Wt = Wo^T [1024][1024], out fp32.
// 64x128 tile, grid (64,8) = 512 blocks; one-barrier LDS dbuf.

__global__ __launch_bounds__(BLOCK) void gemm_out_kernel(
    const short* __restrict__ A, const short* __restrict__ Wt,
    const float* __restrict__ bias, float* __restrict__ Out) {
  const int Kd = 1024;
  int m0 = blockIdx.x * 64, n0 = blockIdx.y * 128;
  int t = threadIdx.x;
  int lane = t & 63, wv = t >> 6;
  int quad = lane >> 4, lc = lane & 15;
  int wy = wv >> 1, wx = wv & 1;  // wave tile: rows wy*32, cols wx*64
  __shared__ short As[2][64 * 32];
  __shared__ short Bs[2][128 * 32];
  int r0 = t >> 2, c0 = (t & 3) * 8;
  f32x4 acc[2][4] = {};
  const short* Arow0 = A + (size_t)(m0 + r0) * Kd + c0;  // r0 covers 0..63
  const short* Brow0 = Wt + (size_t)(n0 + r0) * Kd + c0;
  const short* Brow1 = Wt + (size_t)(n0 + r0 + 64) * Kd + c0;
  GLD_LDS16(Arow0, &As[0][8 * t]);
  GLD_LDS16(Brow0, &Bs[0][8 * t]);
  GLD_LDS16(Brow1, &Bs[0][8 * t + 2048]);
  int cur = 0;
  for (int k0 = 0; k0 < Kd; k0 += 32) {
    __syncthreads();
    if (k0 + 32 < Kd) {
      int nxt = cur ^ 1;
      GLD_LDS16(Arow0 + k0 + 32, &As[nxt][8 * t]);
      GLD_LDS16(Brow0 + k0 + 32, &Bs[nxt][8 * t]);
      GLD_LDS16(Brow1 + k0 + 32, &Bs[nxt][8 * t + 2048]);
    }
    bf16x8 af[2], bf[4];
#pragma unroll
    for (int i = 0; i < 2; i++)
      af[i] = *(const bf16x8*)&As[cur][(wy * 32 + i * 16 + lc) * 32 + quad * 8];
#pragma unroll
    for (int i = 0; i < 4; i++)
      bf[i] = *(const bf16x8*)&Bs[cur][(wx * 64 + i * 16 + lc) * 32 + quad * 8];
#pragma unroll
    for (int mi = 0; mi < 2; mi++)
#pragma unroll
      for (int ni = 0; ni < 4; ni++)
        acc[mi][ni] = __builtin_amdgcn_mfma_f32_16x16x32_bf16(af[mi], bf[ni], acc[mi][ni], 0, 0, 0);
    cur ^= 1;
  }
#pragma unroll
  for (int mi = 0; mi < 2; mi++) {
    int row = m0 + wy * 32 + mi * 16 + quad * 4;
#pragma unroll
    for (int ni = 0; ni < 4; ni++) {
      int col = n0 + wx * 64 + ni * 16 + lc;
      float bb = bias[col];
#pragma unroll
      for (int r = 0; r < 4; r++)
        Out[(size_t)(row + r) * 1024 + col] = acc[mi][ni][r] + bb;
    }
  }
}

// ---------------- flash attention v9 ----------------
// Grid 1024 = 32 bh x 32 strip-pairs; strip = 32 q rows; pair (s, 63-s) ->
// uniform 33 key-tiles/block. Block = 128 threads = 2 waves, each wave owns
// one 32-key half of every 64-key tile (all-active). v7-verified pieces:
// stride-72 LDS, named prefetch scalars, packed P, 32x32x16 MFMA.
// C-layout: col=lane&31 (q), row=(reg&3)+8*(reg>>2)+4*(lane>>5) (key).
// kh-partials exactly additive (fixed-max softmax); combine via dead P LDS.

__global__ __launch_bounds__(128, 4) void attn_kernel(
    const short* __restrict__ Q, const short* __restrict__ K,
    const short* __restrict__ Vt, short* __restrict__ Oa) {
  int bh = blockIdx.x >> 5;    // 0..31
  int pair = blockIdx.x & 31;  // 0..31
  int t = threadIdx.x;
  int lane = t & 63, w = t >> 6;  // w = key-half
  int ln = lane & 31, lh = lane >> 5;
  const short* Qb = Q + (size_t)bh * 2048 * 64;
  const short* Kb = K + (size_t)bh * 2048 * 64;
  const short* Vg = Vt + (size_t)bh * 64 * 2048;
  int b = bh >> 4, h = bh & 15;

  __shared__ short Kt[64 * 72];     // [key][d], stride 72
  __shared__ short Vs[64 * 72];     // [d][key], stride 72
  __shared__ __align__(16) short Ps[2][32 * 72];  // per-wave P; reused as fp32 O-combine
  __shared__ float lx[64];
  short* Pw = Ps[w];

  int srow = t >> 1;        // 0..63
  int scol = (t & 1) * 32;  // 0 or 32 shorts
  const float M2 = 14.5f;   // fixed softmax max, log2 domain

  for (int sp = 0; sp < 2; sp++) {
    int s = sp ? (63 - pair) : pair;
    int q0 = s * 32;
    int qmax = q0 + 31;
    int ntiles = (s >> 1) + 1;  // 64-key tiles covering keys 0..qmax

    // Q B-frags (n=q, k=d), 4 chunks of 16 d
    bf16x8 qf[4];
#pragma unroll
    for (int c = 0; c < 4; c++)
      qf[c] = *(const bf16x8*)&Qb[(size_t)(q0 + ln) * 64 + c * 16 + lh * 8];

    f32x16 O0 = {}, O1 = {};
    float lsum = 0.f;

    // prologue: stage tile 0 (named scalars -- arrays spill to scratch!)
    int4 ka0 = *(const int4*)&Kb[(size_t)srow * 64 + scol];
    int4 ka1 = *(const int4*)&Kb[(size_t)srow * 64 + scol + 8];
    int4 ka2 = *(const int4*)&Kb[(size_t)srow * 64 + scol + 16];
    int4 ka3 = *(const int4*)&Kb[(size_t)srow * 64 + scol + 24];
    int4 va0 = *(const int4*)&Vg[(size_t)srow * 2048 + scol];
    int4 va1 = *(const int4*)&Vg[(size_t)srow * 2048 + scol + 8];
    int4 va2 = *(const int4*)&Vg[(size_t)srow * 2048 + scol + 16];
    int4 va3 = *(const int4*)&Vg[(size_t)srow * 2048 + scol + 24];
    __syncthreads();  // previous strip's readers done
    *(int4*)&Kt[srow * 72 + scol] = ka0;
    *(int4*)&Kt[srow * 72 + scol + 8] = ka1;
    *(int4*)&Kt[srow * 72 + scol + 16] = ka2;
    *(int4*)&Kt[srow * 72 + scol + 24] = ka3;
    *(int4*)&Vs[srow * 72 + scol] = va0;
    *(int4*)&Vs[srow * 72 + scol + 8] = va1;
    *(int4*)&Vs[srow * 72 + scol + 16] = va2;
    *(int4*)&Vs[srow * 72 + scol + 24] = va3;
    __syncthreads();

    for (int kt = 0; kt < ntiles; kt++) {
      bool more = (kt + 1 < ntiles);
      if (more) {  // prefetch next tile into named regs
        int kb2 = (kt + 1) * 64;
        ka0 = *(const int4*)&Kb[(size_t)(kb2 + srow) * 64 + scol];
        ka1 = *(const int4*)&Kb[(size_t)(kb2 + srow) * 64 + scol + 8];
        ka2 = *(const int4*)&Kb[(size_t)(kb2 + srow) * 64 + scol + 16];
        ka3 = *(const int4*)&Kb[(size_t)(kb2 + srow) * 64 + scol + 24];
        va0 = *(const int4*)&Vg[(size_t)srow * 2048 + kb2 + scol];
        va1 = *(const int4*)&Vg[(size_t)srow * 2048 + kb2 + scol + 8];
        va2 = *(const int4*)&Vg[(size_t)srow * 2048 + kb2 + scol + 16];
        va3 = *(const int4*)&Vg[(size_t)srow * 2048 + kb2 + scol + 24];
      }
      int grpbase = kt * 64 + w * 32;      // wave-uniform 32-key group
      if (grpbase <= qmax) {               // wave active on this tile
        // S^T = K(group) * Q^T : C[m=key32][n=q32]
        f32x16 S = {};
#pragma unroll
        for (int c = 0; c < 4; c++) {
          bf16x8 kf = *(const bf16x8*)&Kt[(w * 32 + ln) * 72 + c * 16 + lh * 8];
          S = __builtin_amdgcn_mfma_f32_32x32x16_bf16(kf, qf[c], S, 0, 0, 0);
        }
        if (kt == ntiles - 1) {  // diagonal tile: mask key > q
          int qg = q0 + ln;
#pragma unroll
          for (int reg = 0; reg < 16; reg++) {
            int key = grpbase + (reg & 3) + 8 * (reg >> 2) + 4 * lh;
            if (key > qg) S[reg] = -3.0e38f;
          }
        }
        // p = exp2(s - M2); accumulate l; pack 4 keys -> b64 (slots 0..31)
#pragma unroll
        for (int g = 0; g < 4; g++) {
          unsigned u[4];
#pragma unroll
          for (int i = 0; i < 4; i++) {
            union { float f; unsigned v; } cc;
            cc.f = __builtin_amdgcn_exp2f(S[g * 4 + i] - M2);
            lsum += cc.f;
            u[i] = cc.v + 0x8000u;  // round-half-up before truncate
          }
          int2 pk;
          pk.x = (int)__builtin_amdgcn_perm(u[1], u[0], 0x07060302);
          pk.y = (int)__builtin_amdgcn_perm(u[3], u[2], 0x07060302);
          *(int2*)&Pw[ln * 72 + g * 8 + lh * 4] = pk;
        }
        // PV over this wave's 32 keys (per-wave LDS, in-order, no barrier)
#pragma unroll
        for (int c2 = 0; c2 < 2; c2++) {
          bf16x8 pf = *(const bf16x8*)&Pw[ln * 72 + c2 * 16 + lh * 8];
          int vb = w * 32 + c2 * 16 + lh * 8;  // key within tile
          bf16x8 v0 = *(const bf16x8*)&Vs[ln * 72 + vb];
          bf16x8 v1 = *(const bf16x8*)&Vs[(32 + ln) * 72 + vb];
          O0 = __builtin_amdgcn_mfma_f32_32x32x16_bf16(v0, pf, O0, 0, 0, 0);
          O1 = __builtin_amdgcn_mfma_f32_32x32x16_bf16(v1, pf, O1, 0, 0, 0);
        }
      }
      if (more) {  // commit prefetched tile (uniform barriers)
        __syncthreads();
        *(int4*)&Kt[srow * 72 + scol] = ka0;
        *(int4*)&Kt[srow * 72 + scol + 8] = ka1;
        *(int4*)&Kt[srow * 72 + scol + 16] = ka2;
        *(int4*)&Kt[srow * 72 + scol + 24] = ka3;
        *(int4*)&Vs[srow * 72 + scol] = va0;
        *(int4*)&Vs[srow * 72 + scol + 8] = va1;
        *(int4*)&Vs[srow * 72 + scol + 16] = va2;
        *(int4*)&Vs[srow * 72 + scol + 24] = va3;
        __syncthreads();
      }
    }

    // ---- combine key-half partials through LDS (P region is dead) ----
    float* ob = (float*)&Ps[0][0];  // [((dh*16+reg)*2+lh)*32+ln] fp32, 8 KB
    __syncthreads();                // all P reads done before overwrite
    if (w == 1) {
#pragma unroll
      for (int dh = 0; dh < 2; dh++)
#pragma unroll
        for (int reg = 0; reg < 16; reg++)
          ob[((dh * 16 + reg) * 2 + lh) * 32 + ln] = dh ? O1[reg] : O0[reg];
      lx[lane] = lsum;
    }
    __syncthreads();
    if (w == 0) {
#pragma unroll
      for (int reg = 0; reg < 16; reg++) {
        O0[reg] += ob[((0 * 16 + reg) * 2 + lh) * 32 + ln];
        O1[reg] += ob[((1 * 16 + reg) * 2 + lh) * 32 + ln];
      }
      float lt = lsum + lx[lane];
      lt += __shfl_xor(lt, 32, 64);
      float inv = 1.0f / lt;
      size_t rowbase = (size_t)(b * 2048 + q0 + ln) * 1024 + h * 64;
#pragma unroll
      for (int dh = 0; dh < 2; dh++)
#pragma unroll
        for (int g = 0; g < 4; g++) {
          alignas(8) short pk[4];
#pragma unroll
          for (int i = 0; i < 4; i++) {
            float v = dh ? O1[g * 4 + i] : O0[g * 4 + i];
            pk[i] = f2bf(v * inv);
          }
          *(int2*)&Oa[rowbase + dh * 32 + g * 8 + lh * 4] = *(const int2*)pk;
        }
    }
    __syncthreads();  // protect ob/lx before next strip
  }
}

// ---------------- launcher ----------------

extern "C" void kernel_launch(void* const* d_in, const int* in_sizes, int n_in,
                              void* d_out, int out_size, void* d_ws, size_t ws_size,
                              hipStream_t stream) {
  const float* x = (const float*)d_in[0];
  const float* Wq = (const float*)d_in[1];
  const float* bq = (const float*)d_in[2];
  const float* Wk = (const float*)d_in[3];
  const float* bk = (const float*)d_in[4];
  const float* Wv = (const float*)d_in[5];
  const float* bv = (const float*)d_in[6];
  const float* Wo = (const float*)d_in[7];
  const float* bo = (const float*)d_in[8];
  char* ws = (char*)d_ws;
  const size_t MB = 1024 * 1024;
  short* xb = (short*)(ws);               // 8 MiB  [4096][1024] bf16
  short* Wtqkv = (short*)(ws + 8 * MB);   // 6 MiB  [3072][1024] bf16
  short* Wto = (short*)(ws + 14 * MB);    // 2 MiB  [1024][1024] bf16
  short* Qb = (short*)(ws + 17 * MB);     // 8 MiB  [2][16][2048][64] bf16 (prescaled)
  short* Kb = (short*)(ws + 25 * MB);     // 8 MiB  [2][16][2048][64] bf16
  short* Vb = (short*)(ws + 33 * MB);     // 8 MiB  V^T [2][16][64][2048] bf16
  short* Att = (short*)(ws + 41 * MB);    // 8 MiB  [4096][1024] bf16
  float* out = (float*)d_out;

  cvt_x_kernel<<<2048, BLOCK, 0, stream>>>(x, xb);
  cvt_w_kernel<<<dim3(32, 32, 4), BLOCK, 0, stream>>>(Wq, Wk, Wv, Wo, Wtqkv, Wto);
  gemm_qkv_kernel<<<dim3(32, 24), BLOCK, 0, stream>>>(xb, Wtqkv, bq, bk, bv, Qb, Kb, Vb);
  attn_kernel<<<1024, 128, 0, stream>>>(Qb, Kb, Vb, Att);
  gemm_out_kernel<<<dim3(64, 8), BLOCK, 0, stream>>>(Att, Wto, bo, out);
}

// Round 10
// 194.262 us; speedup vs baseline: 1.2931x; 1.1154x over previous
//
#include <hip/hip_runtime.h>
#include <math.h>

// MultiHeadAttention: B=2, T=2048, C=1024, H=16, D=64, causal, fp32 in/out.
// R10: attn = v7 shape (64q strip-pairs, 512 blocks, 4 waves) with
// (qhalf x keyhalf) all-active split + one-barrier async global_load_lds
// double-buffer + XOR-swizzled stride-64 K/V LDS (slot s of row r holds
// global 16B-chunk s^(r&7)). No register staging at all (v8 scratch lesson).
// Fixed-max softmax (p = exp2(s2 - 14.5), Q prescaled by 0.125*log2(e)).

#define BLOCK 256

typedef __attribute__((ext_vector_type(8))) short bf16x8;
typedef __attribute__((ext_vector_type(4))) float f32x4;
typedef __attribute__((ext_vector_type(16))) float f32x16;

__device__ inline short f2bf(float f) {
  union { float f; unsigned u; } c; c.f = f;
  unsigned u = c.u;
  unsigned r = (u + 0x7fffu + ((u >> 16) & 1u)) >> 16;  // RNE
  return (short)r;
}

// async global->LDS, 16B per lane; LDS dest must be wave-uniform base + lane*16
#define GLD_LDS16(g, l)                                            \
  __builtin_amdgcn_global_load_lds(                                \
      (const __attribute__((address_space(1))) unsigned int*)(g),  \
      (__attribute__((address_space(3))) unsigned int*)(l), 16, 0, 0)

// ---------------- conversion kernels ----------------

__global__ void cvt_x_kernel(const float* __restrict__ x, short* __restrict__ xb) {
  int i = (blockIdx.x * BLOCK + threadIdx.x) * 8;
  float4 a = *(const float4*)(x + i);
  float4 b = *(const float4*)(x + i + 4);
  alignas(16) short o[8];
  o[0] = f2bf(a.x); o[1] = f2bf(a.y); o[2] = f2bf(a.z); o[3] = f2bf(a.w);
  o[4] = f2bf(b.x); o[5] = f2bf(b.y); o[6] = f2bf(b.z); o[7] = f2bf(b.w);
  *(int4*)(xb + i) = *(int4*)o;
}

// W [1024 (in,k)][1024 (out,n)] fp32 -> Wt [n][k] bf16 (tiled transpose)
__global__ void cvt_w_kernel(const float* __restrict__ Wq, const float* __restrict__ Wk,
                             const float* __restrict__ Wv, const float* __restrict__ Wo,
                             short* __restrict__ Wtqkv, short* __restrict__ Wto) {
  __shared__ float tile[32][33];
  int z = blockIdx.z;
  const float* W = (z == 0) ? Wq : (z == 1) ? Wk : (z == 2) ? Wv : Wo;
  short* outp = (z == 3) ? Wto : (Wtqkv + (size_t)z * 1024 * 1024);
  int k0 = blockIdx.x * 32, n0 = blockIdx.y * 32;
  int tr = threadIdx.x >> 5, tc = threadIdx.x & 31;
#pragma unroll
  for (int i = 0; i < 4; i++)
    tile[tr + i * 8][tc] = W[(k0 + tr + i * 8) * 1024 + n0 + tc];
  __syncthreads();
#pragma unroll
  for (int i = 0; i < 4; i++)
    outp[(n0 + tr + i * 8) * 1024 + k0 + tc] = f2bf(tile[tc][tr + i * 8]);
}

// ---------------- fused QKV GEMM ----------------
// A [4096][1024] bf16 (x), Wt [3072][1024] bf16 (B^T). BK=32, one-barrier
// LDS double-buffer: barrier -> issue loads(next) -> compute(cur).
// Q -> [B,H,T,D] prescaled by 0.125*log2(e); K -> [B,H,T,D];
// V -> V^T [B,H,D,T] (natural key order), b64-packed stores.

__global__ __launch_bounds__(BLOCK) void gemm_qkv_kernel(
    const short* __restrict__ A, const short* __restrict__ Wt,
    const float* __restrict__ bq, const float* __restrict__ bk,
    const float* __restrict__ bv,
    short* __restrict__ Qo, short* __restrict__ Ko, short* __restrict__ Vo) {
  const int Kd = 1024;
  const float QSCL = 0.18033688011f;  // 0.125 * log2(e)
  int m0 = blockIdx.x * 128, n0 = blockIdx.y * 128;
  int t = threadIdx.x;
  int lane = t & 63, wv = t >> 6;
  int quad = lane >> 4, lc = lane & 15;
  int wy = wv >> 1, wx = wv & 1;
  __shared__ short As[2][128 * 32];
  __shared__ short Bs[2][128 * 32];
  f32x4 acc[4][4] = {};
  int r0 = t >> 2, c0 = (t & 3) * 8;  // As[p][r0*32+c0] == As[p][8*t]
  const short* Arow0 = A + (size_t)(m0 + r0) * Kd + c0;
  const short* Arow1 = A + (size_t)(m0 + r0 + 64) * Kd + c0;
  const short* Brow0 = Wt + (size_t)(n0 + r0) * Kd + c0;
  const short* Brow1 = Wt + (size_t)(n0 + r0 + 64) * Kd + c0;
  // prologue: stage k=0 into buf 0
  GLD_LDS16(Arow0, &As[0][8 * t]);
  GLD_LDS16(Arow1, &As[0][8 * t + 2048]);
  GLD_LDS16(Brow0, &Bs[0][8 * t]);
  GLD_LDS16(Brow1, &Bs[0][8 * t + 2048]);
  int cur = 0;
  for (int k0 = 0; k0 < Kd; k0 += 32) {
    __syncthreads();  // drains cur's loads (issued one full compute ago)
    if (k0 + 32 < Kd) {
      int nxt = cur ^ 1;
      GLD_LDS16(Arow0 + k0 + 32, &As[nxt][8 * t]);
      GLD_LDS16(Arow1 + k0 + 32, &As[nxt][8 * t + 2048]);
      GLD_LDS16(Brow0 + k0 + 32, &Bs[nxt][8 * t]);
      GLD_LDS16(Brow1 + k0 + 32, &Bs[nxt][8 * t + 2048]);
    }
    bf16x8 af[4], bf[4];
#pragma unroll
    for (int i = 0; i < 4; i++)
      af[i] = *(const bf16x8*)&As[cur][(wy * 64 + i * 16 + lc) * 32 + quad * 8];
#pragma unroll
    for (int i = 0; i < 4; i++)
      bf[i] = *(const bf16x8*)&Bs[cur][(wx * 64 + i * 16 + lc) * 32 + quad * 8];
#pragma unroll
    for (int mi = 0; mi < 4; mi++)
#pragma unroll
      for (int ni = 0; ni < 4; ni++)
        acc[mi][ni] = __builtin_amdgcn_mfma_f32_16x16x32_bf16(af[mi], bf[ni], acc[mi][ni], 0, 0, 0);
    cur ^= 1;
  }
#pragma unroll
  for (int mi = 0; mi < 4; mi++) {
    int row = m0 + wy * 64 + mi * 16 + quad * 4;
#pragma unroll
    for (int ni = 0; ni < 4; ni++) {
      int col = n0 + wx * 64 + ni * 16 + lc;
      int which = col >> 10;  // block-uniform (n-tile never straddles 1024)
      int hd = col & 1023;
      int h = hd >> 6, d = hd & 63;
      float bb = (which == 0) ? bq[hd] : (which == 1) ? bk[hd] : bv[hd];
      if (which == 2) {  // V^T [b,h,d,t], pack 4 consecutive t
        alignas(8) short pk[4];
#pragma unroll
        for (int r = 0; r < 4; r++) pk[r] = f2bf(acc[mi][ni][r] + bb);
        int b = row >> 11, tt = row & 2047;
        *(int2*)&Vo[((size_t)(b * 16 + h) * 64 + d) * 2048 + tt] = *(const int2*)pk;
      } else {
#pragma unroll
        for (int r = 0; r < 4; r++) {
          int rw = row + r;
          int b = rw >> 11, tt = rw & 2047;
          float val = acc[mi][ni][r] + bb;
          if (which == 0) {
            Qo[((size_t)(b * 16 + h) * 2048 + tt) * 64 + d] = f2bf(val * QSCL);
          } else {
            Ko[((size_t)(b * 16 + h) * 2048 + tt) * 64 + d] = f2bf(val);
          }
        }
      }
    }
  }
}

// ---------------- out-projection GEMM ----------------
// A = attended [4096][1024] bf16, Wt = Wo^T [1024][1024], out fp32.
// 64x128 tile, grid (64,8) = 512 blocks; one-barrier LDS dbuf.

__global__ __launch_bounds__(BLOCK) void gemm_out_kernel(
    const short* __restrict__ A, const short* __restrict__ Wt,
    const float* __restrict__ bias, float* __restrict__ Out) {
  const int Kd = 1024;
  int m0 = blockIdx.x * 64, n0 = blockIdx.y * 128;
  int t = threadIdx.x;
  int lane = t & 63, wv = t >> 6;
  int quad = lane >> 4, lc = lane & 15;
  int wy = wv >> 1, wx = wv & 1;  // wave tile: rows wy*32, cols wx*64
  __shared__ short As[2][64 * 32];
  __shared__ short Bs[2][128 * 32];
  int r0 = t >> 2, c0 = (t & 3) * 8;
  f32x4 acc[2][4] = {};
  const short* Arow0 = A + (size_t)(m0 + r0) * Kd + c0;  // r0 covers 0..63
  const short* Brow0 = Wt + (size_t)(n0 + r0) * Kd + c0;
  const short* Brow1 = Wt + (size_t)(n0 + r0 + 64) * Kd + c0;
  GLD_LDS16(Arow0, &As[0][8 * t]);
  GLD_LDS16(Brow0, &Bs[0][8 * t]);
  GLD_LDS16(Brow1, &Bs[0][8 * t + 2048]);
  int cur = 0;
  for (int k0 = 0; k0 < Kd; k0 += 32) {
    __syncthreads();
    if (k0 + 32 < Kd) {
      int nxt = cur ^ 1;
      GLD_LDS16(Arow0 + k0 + 32, &As[nxt][8 * t]);
      GLD_LDS16(Brow0 + k0 + 32, &Bs[nxt][8 * t]);
      GLD_LDS16(Brow1 + k0 + 32, &Bs[nxt][8 * t + 2048]);
    }
    bf16x8 af[2], bf[4];
#pragma unroll
    for (int i = 0; i < 2; i++)
      af[i] = *(const bf16x8*)&As[cur][(wy * 32 + i * 16 + lc) * 32 + quad * 8];
#pragma unroll
    for (int i = 0; i < 4; i++)
      bf[i] = *(const bf16x8*)&Bs[cur][(wx * 64 + i * 16 + lc) * 32 + quad * 8];
#pragma unroll
    for (int mi = 0; mi < 2; mi++)
#pragma unroll
      for (int ni = 0; ni < 4; ni++)
        acc[mi][ni] = __builtin_amdgcn_mfma_f32_16x16x32_bf16(af[mi], bf[ni], acc[mi][ni], 0, 0, 0);
    cur ^= 1;
  }
#pragma unroll
  for (int mi = 0; mi < 2; mi++) {
    int row = m0 + wy * 32 + mi * 16 + quad * 4;
#pragma unroll
    for (int ni = 0; ni < 4; ni++) {
      int col = n0 + wx * 64 + ni * 16 + lc;
      float bb = bias[col];
#pragma unroll
      for (int r = 0; r < 4; r++)
        Out[(size_t)(row + r) * 1024 + col] = acc[mi][ni][r] + bb;
    }
  }
}

// ---------------- flash attention v10 ----------------
// Grid 512 = 32 bh x 16 strip-pairs; strip = 64 q; pair (s, 31-s) -> uniform
// 33 key-tiles/block. 4 waves = qhalf(w&1) x keyhalf(w>>1), ALL active every
// tile. One-barrier async dbuf: barrier -> global_load_lds(next buf) ->
// compute(cur buf). K/V LDS stride 64 with XOR swizzle: slot s of row r
// holds global chunk s^(r&7); readers use chunk ch at slot ch^(r&7).
// 32x32x16 MFMA. C-layout: col=lane&31 (q), row=(reg&3)+8*(reg>>2)+4*(lane>>5).
// kh partials exactly additive (fixed-max softmax); combine via dead P LDS.

__global__ __launch_bounds__(BLOCK, 2) void attn_kernel(
    const short* __restrict__ Q, const short* __restrict__ K,
    const short* __restrict__ Vt, short* __restrict__ Oa) {
  int bh = blockIdx.x >> 4;    // 0..31
  int pair = blockIdx.x & 15;  // 0..15
  int t = threadIdx.x;
  int lane = t & 63, w = t >> 6;
  int qh = w & 1, kh = w >> 1;
  int ln = lane & 31, lh = lane >> 5;
  const short* Qb = Q + (size_t)bh * 2048 * 64;
  const short* Kb = K + (size_t)bh * 2048 * 64;
  const short* Vg = Vt + (size_t)bh * 64 * 2048;
  int b = bh >> 4, h = bh & 15;

  __shared__ short Kt[2][64 * 64];  // [key][chunk-swizzled d], stride 64
  __shared__ short Vs[2][64 * 64];  // [d][chunk-swizzled key], stride 64
  __shared__ __align__(16) short Ps[4][32 * 72];  // per-wave P; reused as fp32 O-combine
  __shared__ float lx[2][64];
  short* Pw = Ps[w];

  int srow = t >> 3;       // staging row sub-index 0..31 (i*32 + srow = row)
  int sw = (t & 7) ^ 0;    // chunk slot 0..7 (slot index == lane&7)
  const float M2 = 14.5f;  // fixed softmax max, log2 domain
  int xk = ln & 7;         // reader xor for K rows (key&7) and V rows (d&7)

  for (int sp = 0; sp < 2; sp++) {
    int s = sp ? (31 - pair) : pair;
    int q0 = s * 64;
    int q0w = q0 + qh * 32;
    int qmaxw = q0w + 31;
    int ntiles = s + 1;

    // Q B-frags (n=q, k=d), 4 chunks of 16 d
    bf16x8 qf[4];
#pragma unroll
    for (int c = 0; c < 4; c++)
      qf[c] = *(const bf16x8*)&Qb[(size_t)(q0w + ln) * 64 + c * 16 + lh * 8];

    f32x16 O0 = {}, O1 = {};
    float lsum = 0.f;

    // prologue: async-stage tile 0 into buf 0 (swizzled: thread t covers
    // row r = i*32 + (t>>3), global chunk cg = (t&7)^(r&7), LDS slot t&7)
#pragma unroll
    for (int i = 0; i < 2; i++) {
      int r = i * 32 + srow;
      int cg = sw ^ (r & 7);
      GLD_LDS16(&Kb[(size_t)r * 64 + cg * 8], &Kt[0][i * 2048 + 8 * t]);
      GLD_LDS16(&Vg[(size_t)r * 2048 + cg * 8], &Vs[0][i * 2048 + 8 * t]);
    }
    int cur = 0;
    for (int kt = 0; kt < ntiles; kt++) {
      __syncthreads();  // drains buf[cur]'s async loads (issued a tile ago)
      if (kt + 1 < ntiles) {
        int kb2 = (kt + 1) * 64;
        int nxt = cur ^ 1;
#pragma unroll
        for (int i = 0; i < 2; i++) {
          int r = i * 32 + srow;
          int cg = sw ^ (r & 7);
          GLD_LDS16(&Kb[(size_t)(kb2 + r) * 64 + cg * 8], &Kt[nxt][i * 2048 + 8 * t]);
          GLD_LDS16(&Vg[(size_t)r * 2048 + kb2 + cg * 8], &Vs[nxt][i * 2048 + 8 * t]);
        }
      }
      int grpbase = kt * 64 + kh * 32;  // wave-uniform 32-key group
      if (grpbase <= qmaxw) {           // wave active on this tile
        // S^T = K(group) * Q^T : C[m=key32][n=q32]
        f32x16 S = {};
#pragma unroll
        for (int c = 0; c < 4; c++) {
          int ch = c * 2 + lh;  // 16B d-chunk index
          bf16x8 kf = *(const bf16x8*)&Kt[cur][(kh * 32 + ln) * 64 + (ch ^ xk) * 8];
          S = __builtin_amdgcn_mfma_f32_32x32x16_bf16(kf, qf[c], S, 0, 0, 0);
        }
        if (kt == ntiles - 1) {  // diagonal tile: mask key > q
          int qg = q0w + ln;
#pragma unroll
          for (int reg = 0; reg < 16; reg++) {
            int key = grpbase + (reg & 3) + 8 * (reg >> 2) + 4 * lh;
            if (key > qg) S[reg] = -3.0e38f;
          }
        }
        // p = exp2(s - M2); accumulate l; pack 4 keys -> b64 (slots 0..31)
#pragma unroll
        for (int g = 0; g < 4; g++) {
          unsigned u[4];
#pragma unroll
          for (int i = 0; i < 4; i++) {
            union { float f; unsigned v; } cc;
            cc.f = __builtin_amdgcn_exp2f(S[g * 4 + i] - M2);
            lsum += cc.f;
            u[i] = cc.v + 0x8000u;  // round-half-up before truncate
          }
          int2 pk;
          pk.x = (int)__builtin_amdgcn_perm(u[1], u[0], 0x07060302);
          pk.y = (int)__builtin_amdgcn_perm(u[3], u[2], 0x07060302);
          *(int2*)&Pw[ln * 72 + g * 8 + lh * 4] = pk;
        }
        // PV over this wave's 32 keys (per-wave LDS, in-order, no barrier)
#pragma unroll
        for (int c2 = 0; c2 < 2; c2++) {
          bf16x8 pf = *(const bf16x8*)&Pw[ln * 72 + c2 * 16 + lh * 8];
          int ch = kh * 4 + c2 * 2 + lh;  // 16B key-chunk within tile
          bf16x8 v0 = *(const bf16x8*)&Vs[cur][ln * 64 + (ch ^ xk) * 8];
          bf16x8 v1 = *(const bf16x8*)&Vs[cur][(32 + ln) * 64 + (ch ^ xk) * 8];
          O0 = __builtin_amdgcn_mfma_f32_32x32x16_bf16(v0, pf, O0, 0, 0, 0);
          O1 = __builtin_amdgcn_mfma_f32_32x32x16_bf16(v1, pf, O1, 0, 0, 0);
        }
      }
      cur ^= 1;
    }

    // ---- combine keyhalf partials through LDS (P region is dead) ----
    float* ob = (float*)&Ps[0][0];  // [qh][((dh*16+reg)*2+lh)*32+ln] fp32
    __syncthreads();                // all P reads done before overwrite
    if (kh == 1) {
      float* obw = ob + qh * 2048;
#pragma unroll
      for (int dh = 0; dh < 2; dh++)
#pragma unroll
        for (int reg = 0; reg < 16; reg++)
          obw[((dh * 16 + reg) * 2 + lh) * 32 + ln] = dh ? O1[reg] : O0[reg];
      lx[qh][lane] = lsum;
    }
    __syncthreads();
    if (kh == 0) {
      float* obw = ob + qh * 2048;
#pragma unroll
      for (int reg = 0; reg < 16; reg++) {
        O0[reg] += obw[((0 * 16 + reg) * 2 + lh) * 32 + ln];
        O1[reg] += obw[((1 * 16 + reg) * 2 + lh) * 32 + ln];
      }
      float lt = lsum + lx[qh][lane];
      lt += __shfl_xor(lt, 32, 64);
      float inv = 1.0f / lt;
      size_t rowbase = (size_t)(b * 2048 + q0w + ln) * 1024 + h * 64;
#pragma unroll
      for (int dh = 0; dh < 2; dh++)
#pragma unroll
        for (int g = 0; g < 4; g++) {
          alignas(8) short pk[4];
#pragma unroll
          for (int i = 0; i < 4; i++) {
            float v = dh ? O1[g * 4 + i] : O0[g * 4 + i];
            pk[i] = f2bf(v * inv);
          }
          *(int2*)&Oa[rowbase + dh * 32 + g * 8 + lh * 4] = *(const int2*)pk;
        }
    }
    // next strip's first __syncthreads orders Ps reuse after ob/lx reads
  }
}

// ---------------- launcher ----------------

extern "C" void kernel_launch(void* const* d_in, const int* in_sizes, int n_in,
                              void* d_out, int out_size, void* d_ws, size_t ws_size,
                              hipStream_t stream) {
  const float* x = (const float*)d_in[0];
  const float* Wq = (const float*)d_in[1];
  const float* bq = (const float*)d_in[2];
  const float* Wk = (const float*)d_in[3];
  const float* bk = (const float*)d_in[4];
  const float* Wv = (const float*)d_in[5];
  const float* bv = (const float*)d_in[6];
  const float* Wo = (const float*)d_in[7];
  const float* bo = (const float*)d_in[8];
  char* ws = (char*)d_ws;
  const size_t MB = 1024 * 1024;
  short* xb = (short*)(ws);               // 8 MiB  [4096][1024] bf16
  short* Wtqkv = (short*)(ws + 8 * MB);   // 6 MiB  [3072][1024] bf16
  short* Wto = (short*)(ws + 14 * MB);    // 2 MiB  [1024][1024] bf16
  short* Qb = (short*)(ws + 17 * MB);     // 8 MiB  [2][16][2048][64] bf16 (prescaled)
  short* Kb = (short*)(ws + 25 * MB);     // 8 MiB  [2][16][2048][64] bf16
  short* Vb = (short*)(ws + 33 * MB);     // 8 MiB  V^T [2][16][64][2048] bf16
  short* Att = (short*)(ws + 41 * MB);    // 8 MiB  [4096][1024] bf16
  float* out = (float*)d_out;

  cvt_x_kernel<<<2048, BLOCK, 0, stream>>>(x, xb);
  cvt_w_kernel<<<dim3(32, 32, 4), BLOCK, 0, stream>>>(Wq, Wk, Wv, Wo, Wtqkv, Wto);
  gemm_qkv_kernel<<<dim3(32, 24), BLOCK, 0, stream>>>(xb, Wtqkv, bq, bk, bv, Qb, Kb, Vb);
  attn_kernel<<<512, BLOCK, 0, stream>>>(Qb, Kb, Vb, Att);
  gemm_out_kernel<<<dim3(64, 8), BLOCK, 0, stream>>>(Att, Wto, bo, out);
}

// Round 11
// 186.072 us; speedup vs baseline: 1.3500x; 1.0440x over previous
//
#include <hip/hip_runtime.h>
#include <math.h>

// MultiHeadAttention: B=2, T=2048, C=1024, H=16, D=64, causal, fp32 in/out.
// R11: attn = R10 (async one-barrier dbuf, qh x kh all-active, xor-swizzled
// LDS) + XCD-aware block remap: all 16 strip-pairs of a bh land on one XCD
// (4 bh/XCD -> K+V 4MB fits that XCD's L2; kills the 8x cross-XCD refetch).
// cvt_x + cvt_w merged into one launch. Fixed-max softmax throughout.

#define BLOCK 256

typedef __attribute__((ext_vector_type(8))) short bf16x8;
typedef __attribute__((ext_vector_type(4))) float f32x4;
typedef __attribute__((ext_vector_type(16))) float f32x16;

__device__ inline short f2bf(float f) {
  union { float f; unsigned u; } c; c.f = f;
  unsigned u = c.u;
  unsigned r = (u + 0x7fffu + ((u >> 16) & 1u)) >> 16;  // RNE
  return (short)r;
}

// async global->LDS, 16B per lane; LDS dest must be wave-uniform base + lane*16
#define GLD_LDS16(g, l)                                            \
  __builtin_amdgcn_global_load_lds(                                \
      (const __attribute__((address_space(1))) unsigned int*)(g),  \
      (__attribute__((address_space(3))) unsigned int*)(l), 16, 0, 0)

// ---------------- fused conversion kernel ----------------
// z = 0..3: W transpose (Wq/Wk/Wv/Wo -> [n][k] bf16); z = 4..5: x -> bf16.

__global__ void cvt_all_kernel(const float* __restrict__ x,
                               const float* __restrict__ Wq, const float* __restrict__ Wk,
                               const float* __restrict__ Wv, const float* __restrict__ Wo,
                               short* __restrict__ xb,
                               short* __restrict__ Wtqkv, short* __restrict__ Wto) {
  int z = blockIdx.z;
  if (z >= 4) {  // x conversion: 2048 virtual blocks x 256 thr x 8 elems
    int blk = blockIdx.x + (blockIdx.y << 5) + ((z - 4) << 10);
    int i = (blk * 256 + threadIdx.x) * 8;
    float4 a = *(const float4*)(x + i);
    float4 b = *(const float4*)(x + i + 4);
    alignas(16) short o[8];
    o[0] = f2bf(a.x); o[1] = f2bf(a.y); o[2] = f2bf(a.z); o[3] = f2bf(a.w);
    o[4] = f2bf(b.x); o[5] = f2bf(b.y); o[6] = f2bf(b.z); o[7] = f2bf(b.w);
    *(int4*)(xb + i) = *(int4*)o;
    return;
  }
  __shared__ float tile[32][33];
  const float* W = (z == 0) ? Wq : (z == 1) ? Wk : (z == 2) ? Wv : Wo;
  short* outp = (z == 3) ? Wto : (Wtqkv + (size_t)z * 1024 * 1024);
  int k0 = blockIdx.x * 32, n0 = blockIdx.y * 32;
  int tr = threadIdx.x >> 5, tc = threadIdx.x & 31;
#pragma unroll
  for (int i = 0; i < 4; i++)
    tile[tr + i * 8][tc] = W[(k0 + tr + i * 8) * 1024 + n0 + tc];
  __syncthreads();
#pragma unroll
  for (int i = 0; i < 4; i++)
    outp[(n0 + tr + i * 8) * 1024 + k0 + tc] = f2bf(tile[tc][tr + i * 8]);
}

// ---------------- fused QKV GEMM ----------------
// A [4096][1024] bf16 (x), Wt [3072][1024] bf16 (B^T). BK=32, one-barrier
// LDS double-buffer: barrier -> issue loads(next) -> compute(cur).
// Q -> [B,H,T,D] prescaled by 0.125*log2(e); K -> [B,H,T,D];
// V -> V^T [B,H,D,T] (natural key order), b64-packed stores.

__global__ __launch_bounds__(BLOCK) void gemm_qkv_kernel(
    const short* __restrict__ A, const short* __restrict__ Wt,
    const float* __restrict__ bq, const float* __restrict__ bk,
    const float* __restrict__ bv,
    short* __restrict__ Qo, short* __restrict__ Ko, short* __restrict__ Vo) {
  const int Kd = 1024;
  const float QSCL = 0.18033688011f;  // 0.125 * log2(e)
  int m0 = blockIdx.x * 128, n0 = blockIdx.y * 128;
  int t = threadIdx.x;
  int lane = t & 63, wv = t >> 6;
  int quad = lane >> 4, lc = lane & 15;
  int wy = wv >> 1, wx = wv & 1;
  __shared__ short As[2][128 * 32];
  __shared__ short Bs[2][128 * 32];
  f32x4 acc[4][4] = {};
  int r0 = t >> 2, c0 = (t & 3) * 8;  // As[p][r0*32+c0] == As[p][8*t]
  const short* Arow0 = A + (size_t)(m0 + r0) * Kd + c0;
  const short* Arow1 = A + (size_t)(m0 + r0 + 64) * Kd + c0;
  const short* Brow0 = Wt + (size_t)(n0 + r0) * Kd + c0;
  const short* Brow1 = Wt + (size_t)(n0 + r0 + 64) * Kd + c0;
  // prologue: stage k=0 into buf 0
  GLD_LDS16(Arow0, &As[0][8 * t]);
  GLD_LDS16(Arow1, &As[0][8 * t + 2048]);
  GLD_LDS16(Brow0, &Bs[0][8 * t]);
  GLD_LDS16(Brow1, &Bs[0][8 * t + 2048]);
  int cur = 0;
  for (int k0 = 0; k0 < Kd; k0 += 32) {
    __syncthreads();  // drains cur's loads (issued one full compute ago)
    if (k0 + 32 < Kd) {
      int nxt = cur ^ 1;
      GLD_LDS16(Arow0 + k0 + 32, &As[nxt][8 * t]);
      GLD_LDS16(Arow1 + k0 + 32, &As[nxt][8 * t + 2048]);
      GLD_LDS16(Brow0 + k0 + 32, &Bs[nxt][8 * t]);
      GLD_LDS16(Brow1 + k0 + 32, &Bs[nxt][8 * t + 2048]);
    }
    bf16x8 af[4], bf[4];
#pragma unroll
    for (int i = 0; i < 4; i++)
      af[i] = *(const bf16x8*)&As[cur][(wy * 64 + i * 16 + lc) * 32 + quad * 8];
#pragma unroll
    for (int i = 0; i < 4; i++)
      bf[i] = *(const bf16x8*)&Bs[cur][(wx * 64 + i * 16 + lc) * 32 + quad * 8];
#pragma unroll
    for (int mi = 0; mi < 4; mi++)
#pragma unroll
      for (int ni = 0; ni < 4; ni++)
        acc[mi][ni] = __builtin_amdgcn_mfma_f32_16x16x32_bf16(af[mi], bf[ni], acc[mi][ni], 0, 0, 0);
    cur ^= 1;
  }
#pragma unroll
  for (int mi = 0; mi < 4; mi++) {
    int row = m0 + wy * 64 + mi * 16 + quad * 4;
#pragma unroll
    for (int ni = 0; ni < 4; ni++) {
      int col = n0 + wx * 64 + ni * 16 + lc;
      int which = col >> 10;  // block-uniform (n-tile never straddles 1024)
      int hd = col & 1023;
      int h = hd >> 6, d = hd & 63;
      float bb = (which == 0) ? bq[hd] : (which == 1) ? bk[hd] : bv[hd];
      if (which == 2) {  // V^T [b,h,d,t], pack 4 consecutive t
        alignas(8) short pk[4];
#pragma unroll
        for (int r = 0; r < 4; r++) pk[r] = f2bf(acc[mi][ni][r] + bb);
        int b = row >> 11, tt = row & 2047;
        *(int2*)&Vo[((size_t)(b * 16 + h) * 64 + d) * 2048 + tt] = *(const int2*)pk;
      } else {
#pragma unroll
        for (int r = 0; r < 4; r++) {
          int rw = row + r;
          int b = rw >> 11, tt = rw & 2047;
          float val = acc[mi][ni][r] + bb;
          if (which == 0) {
            Qo[((size_t)(b * 16 + h) * 2048 + tt) * 64 + d] = f2bf(val * QSCL);
          } else {
            Ko[((size_t)(b * 16 + h) * 2048 + tt) * 64 + d] = f2bf(val);
          }
        }
      }
    }
  }
}

// ---------------- out-projection GEMM ----------------
// A = attended [4096][1024] bf16, Wt = Wo^T [1024][1024], out fp32.
// 64x128 tile, grid (64,8) = 512 blocks; one-barrier LDS dbuf.

__global__ __launch_bounds__(BLOCK) void gemm_out_kernel(
    const short* __restrict__ A, const short* __restrict__ Wt,
    const float* __restrict__ bias, float* __restrict__ Out) {
  const int Kd = 1024;
  int m0 = blockIdx.x * 64, n0 = blockIdx.y * 128;
  int t = threadIdx.x;
  int lane = t & 63, wv = t >> 6;
  int quad = lane >> 4, lc = lane & 15;
  int wy = wv >> 1, wx = wv & 1;  // wave tile: rows wy*32, cols wx*64
  __shared__ short As[2][64 * 32];
  __shared__ short Bs[2][128 * 32];
  int r0 = t >> 2, c0 = (t & 3) * 8;
  f32x4 acc[2][4] = {};
  const short* Arow0 = A + (size_t)(m0 + r0) * Kd + c0;  // r0 covers 0..63
  const short* Brow0 = Wt + (size_t)(n0 + r0) * Kd + c0;
  const short* Brow1 = Wt + (size_t)(n0 + r0 + 64) * Kd + c0;
  GLD_LDS16(Arow0, &As[0][8 * t]);
  GLD_LDS16(Brow0, &Bs[0][8 * t]);
  GLD_LDS16(Brow1, &Bs[0][8 * t + 2048]);
  int cur = 0;
  for (int k0 = 0; k0 < Kd; k0 += 32) {
    __syncthreads();
    if (k0 + 32 < Kd) {
      int nxt = cur ^ 1;
      GLD_LDS16(Arow0 + k0 + 32, &As[nxt][8 * t]);
      GLD_LDS16(Brow0 + k0 + 32, &Bs[nxt][8 * t]);
      GLD_LDS16(Brow1 + k0 + 32, &Bs[nxt][8 * t + 2048]);
    }
    bf16x8 af[2], bf[4];
#pragma unroll
    for (int i = 0; i < 2; i++)
      af[i] = *(const bf16x8*)&As[cur][(wy * 32 + i * 16 + lc) * 32 + quad * 8];
#pragma unroll
    for (int i = 0; i < 4; i++)
      bf[i] = *(const bf16x8*)&Bs[cur][(wx * 64 + i * 16 + lc) * 32 + quad * 8];
#pragma unroll
    for (int mi = 0; mi < 2; mi++)
#pragma unroll
      for (int ni = 0; ni < 4; ni++)
        acc[mi][ni] = __builtin_amdgcn_mfma_f32_16x16x32_bf16(af[mi], bf[ni], acc[mi][ni], 0, 0, 0);
    cur ^= 1;
  }
#pragma unroll
  for (int mi = 0; mi < 2; mi++) {
    int row = m0 + wy * 32 + mi * 16 + quad * 4;
#pragma unroll
    for (int ni = 0; ni < 4; ni++) {
      int col = n0 + wx * 64 + ni * 16 + lc;
      float bb = bias[col];
#pragma unroll
      for (int r = 0; r < 4; r++)
        Out[(size_t)(row + r) * 1024 + col] = acc[mi][ni][r] + bb;
    }
  }
}

// ---------------- flash attention v11 ----------------
// = v10 + XCD-aware block remap: physical block p -> bh = (p&7)*4 + ((p>>3)&3),
// pair = p>>5. All 16 pairs of a bh share p%8 (XCD round-robin heuristic) ->
// that XCD's L2 holds its 4 bh's K+V (4 MB). Grid 512 = 32 bh x 16 pairs;
// strip = 64 q; pair (s, 31-s) -> uniform 33 tiles. 4 waves = qh x kh,
// all active. One-barrier async dbuf; xor-swizzled stride-64 K/V LDS.
// Fixed-max softmax (p = exp2(s2 - 14.5), Q prescaled by 0.125*log2(e)).

__global__ __launch_bounds__(BLOCK, 2) void attn_kernel(
    const short* __restrict__ Q, const short* __restrict__ K,
    const short* __restrict__ Vt, short* __restrict__ Oa) {
  int p = blockIdx.x;
  int bh = ((p & 7) << 2) | ((p >> 3) & 3);  // same bh -> same XCD (p%8)
  int pair = p >> 5;                         // 0..15
  int t = threadIdx.x;
  int lane = t & 63, w = t >> 6;
  int qh = w & 1, kh = w >> 1;
  int ln = lane & 31, lh = lane >> 5;
  const short* Qb = Q + (size_t)bh * 2048 * 64;
  const short* Kb = K + (size_t)bh * 2048 * 64;
  const short* Vg = Vt + (size_t)bh * 64 * 2048;
  int b = bh >> 4, h = bh & 15;

  __shared__ short Kt[2][64 * 64];  // [key][chunk-swizzled d], stride 64
  __shared__ short Vs[2][64 * 64];  // [d][chunk-swizzled key], stride 64
  __shared__ __align__(16) short Ps[4][32 * 72];  // per-wave P; reused as fp32 O-combine
  __shared__ float lx[2][64];
  short* Pw = Ps[w];

  int srow = t >> 3;       // staging row sub-index 0..31 (i*32 + srow = row)
  int sw = t & 7;          // chunk slot 0..7
  const float M2 = 14.5f;  // fixed softmax max, log2 domain
  int xk = ln & 7;         // reader xor (row&7)

  for (int sp = 0; sp < 2; sp++) {
    int s = sp ? (31 - pair) : pair;
    int q0 = s * 64;
    int q0w = q0 + qh * 32;
    int qmaxw = q0w + 31;
    int ntiles = s + 1;

    // Q B-frags (n=q, k=d), 4 chunks of 16 d
    bf16x8 qf[4];
#pragma unroll
    for (int c = 0; c < 4; c++)
      qf[c] = *(const bf16x8*)&Qb[(size_t)(q0w + ln) * 64 + c * 16 + lh * 8];

    f32x16 O0 = {}, O1 = {};
    float lsum = 0.f;

    // prologue: async-stage tile 0 into buf 0 (swizzled: thread t covers
    // row r = i*32 + (t>>3), global chunk cg = (t&7)^(r&7), LDS slot t&7)
#pragma unroll
    for (int i = 0; i < 2; i++) {
      int r = i * 32 + srow;
      int cg = sw ^ (r & 7);
      GLD_LDS16(&Kb[(size_t)r * 64 + cg * 8], &Kt[0][i * 2048 + 8 * t]);
      GLD_LDS16(&Vg[(size_t)r * 2048 + cg * 8], &Vs[0][i * 2048 + 8 * t]);
    }
    int cur = 0;
    for (int kt = 0; kt < ntiles; kt++) {
      __syncthreads();  // drains buf[cur]'s async loads (issued a tile ago)
      if (kt + 1 < ntiles) {
        int kb2 = (kt + 1) * 64;
        int nxt = cur ^ 1;
#pragma unroll
        for (int i = 0; i < 2; i++) {
          int r = i * 32 + srow;
          int cg = sw ^ (r & 7);
          GLD_LDS16(&Kb[(size_t)(kb2 + r) * 64 + cg * 8], &Kt[nxt][i * 2048 + 8 * t]);
          GLD_LDS16(&Vg[(size_t)r * 2048 + kb2 + cg * 8], &Vs[nxt][i * 2048 + 8 * t]);
        }
      }
      int grpbase = kt * 64 + kh * 32;  // wave-uniform 32-key group
      if (grpbase <= qmaxw) {           // wave active on this tile
        // S^T = K(group) * Q^T : C[m=key32][n=q32]
        f32x16 S = {};
#pragma unroll
        for (int c = 0; c < 4; c++) {
          int ch = c * 2 + lh;  // 16B d-chunk index
          bf16x8 kf = *(const bf16x8*)&Kt[cur][(kh * 32 + ln) * 64 + (ch ^ xk) * 8];
          S = __builtin_amdgcn_mfma_f32_32x32x16_bf16(kf, qf[c], S, 0, 0, 0);
        }
        if (kt == ntiles - 1) {  // diagonal tile: mask key > q
          int qg = q0w + ln;
#pragma unroll
          for (int reg = 0; reg < 16; reg++) {
            int key = grpbase + (reg & 3) + 8 * (reg >> 2) + 4 * lh;
            if (key > qg) S[reg] = -3.0e38f;
          }
        }
        // p = exp2(s - M2); accumulate l; pack 4 keys -> b64 (slots 0..31)
#pragma unroll
        for (int g = 0; g < 4; g++) {
          unsigned u[4];
#pragma unroll
          for (int i = 0; i < 4; i++) {
            union { float f; unsigned v; } cc;
            cc.f = __builtin_amdgcn_exp2f(S[g * 4 + i] - M2);
            lsum += cc.f;
            u[i] = cc.v + 0x8000u;  // round-half-up before truncate
          }
          int2 pk;
          pk.x = (int)__builtin_amdgcn_perm(u[1], u[0], 0x07060302);
          pk.y = (int)__builtin_amdgcn_perm(u[3], u[2], 0x07060302);
          *(int2*)&Pw[ln * 72 + g * 8 + lh * 4] = pk;
        }
        // PV over this wave's 32 keys (per-wave LDS, in-order, no barrier)
#pragma unroll
        for (int c2 = 0; c2 < 2; c2++) {
          bf16x8 pf = *(const bf16x8*)&Pw[ln * 72 + c2 * 16 + lh * 8];
          int ch = kh * 4 + c2 * 2 + lh;  // 16B key-chunk within tile
          bf16x8 v0 = *(const bf16x8*)&Vs[cur][ln * 64 + (ch ^ xk) * 8];
          bf16x8 v1 = *(const bf16x8*)&Vs[cur][(32 + ln) * 64 + (ch ^ xk) * 8];
          O0 = __builtin_amdgcn_mfma_f32_32x32x16_bf16(v0, pf, O0, 0, 0, 0);
          O1 = __builtin_amdgcn_mfma_f32_32x32x16_bf16(v1, pf, O1, 0, 0, 0);
        }
      }
      cur ^= 1;
    }

    // ---- combine keyhalf partials through LDS (P region is dead) ----
    float* ob = (float*)&Ps[0][0];  // [qh][((dh*16+reg)*2+lh)*32+ln] fp32
    __syncthreads();                // all P reads done before overwrite
    if (kh == 1) {
      float* obw = ob + qh * 2048;
#pragma unroll
      for (int dh = 0; dh < 2; dh++)
#pragma unroll
        for (int reg = 0; reg < 16; reg++)
          obw[((dh * 16 + reg) * 2 + lh) * 32 + ln] = dh ? O1[reg] : O0[reg];
      lx[qh][lane] = lsum;
    }
    __syncthreads();
    if (kh == 0) {
      float* obw = ob + qh * 2048;
#pragma unroll
      for (int reg = 0; reg < 16; reg++) {
        O0[reg] += obw[((0 * 16 + reg) * 2 + lh) * 32 + ln];
        O1[reg] += obw[((1 * 16 + reg) * 2 + lh) * 32 + ln];
      }
      float lt = lsum + lx[qh][lane];
      lt += __shfl_xor(lt, 32, 64);
      float inv = 1.0f / lt;
      size_t rowbase = (size_t)(b * 2048 + q0w + ln) * 1024 + h * 64;
#pragma unroll
      for (int dh = 0; dh < 2; dh++)
#pragma unroll
        for (int g = 0; g < 4; g++) {
          alignas(8) short pk[4];
#pragma unroll
          for (int i = 0; i < 4; i++) {
            float v = dh ? O1[g * 4 + i] : O0[g * 4 + i];
            pk[i] = f2bf(v * inv);
          }
          *(int2*)&Oa[rowbase + dh * 32 + g * 8 + lh * 4] = *(const int2*)pk;
        }
    }
    // next strip's first __syncthreads orders Ps reuse after ob/lx reads
  }
}

// ---------------- launcher ----------------

extern "C" void kernel_launch(void* const* d_in, const int* in_sizes, int n_in,
                              void* d_out, int out_size, void* d_ws, size_t ws_size,
                              hipStream_t stream) {
  const float* x = (const float*)d_in[0];
  const float* Wq = (const float*)d_in[1];
  const float* bq = (const float*)d_in[2];
  const float* Wk = (const float*)d_in[3];
  const float* bk = (const float*)d_in[4];
  const float* Wv = (const float*)d_in[5];
  const float* bv = (const float*)d_in[6];
  const float* Wo = (const float*)d_in[7];
  const float* bo = (const float*)d_in[8];
  char* ws = (char*)d_ws;
  const size_t MB = 1024 * 1024;
  short* xb = (short*)(ws);               // 8 MiB  [4096][1024] bf16
  short* Wtqkv = (short*)(ws + 8 * MB);   // 6 MiB  [3072][1024] bf16
  short* Wto = (short*)(ws + 14 * MB);    // 2 MiB  [1024][1024] bf16
  short* Qb = (short*)(ws + 17 * MB);     // 8 MiB  [2][16][2048][64] bf16 (prescaled)
  short* Kb = (short*)(ws + 25 * MB);     // 8 MiB  [2][16][2048][64] bf16
  short* Vb = (short*)(ws + 33 * MB);     // 8 MiB  V^T [2][16][64][2048] bf16
  short* Att = (short*)(ws + 41 * MB);    // 8 MiB  [4096][1024] bf16
  float* out = (float*)d_out;

  cvt_all_kernel<<<dim3(32, 32, 6), BLOCK, 0, stream>>>(x, Wq, Wk, Wv, Wo, xb, Wtqkv, Wto);
  gemm_qkv_kernel<<<dim3(32, 24), BLOCK, 0, stream>>>(xb, Wtqkv, bq, bk, bv, Qb, Kb, Vb);
  attn_kernel<<<512, BLOCK, 0, stream>>>(Qb, Kb, Vb, Att);
  gemm_out_kernel<<<dim3(64, 8), BLOCK, 0, stream>>>(Att, Wto, bo, out);
}